// Round 7
// baseline (276.564 us; speedup 1.0000x reference)
//
#include <hip/hip_runtime.h>
#include <hip/hip_bf16.h>

// B=4, H=16, S=2048, D=64
//   S = mask ? -1e9 : QK^T/8 ; O = S@V ; out = log_softmax(O, dim=-1)
// v12: v11 proved the global_load_lds staging win (116->98us) but its XOR
// bank-swizzle measurably conflicts (8.39M cycles) while v10's pitch-144
// rotation measured ZERO. Fix: pre-pad the global bf16 tile images to
// pitch 144B so lane-linear staging reproduces v10's verified layout
// exactly — affine ds_read addresses, no XOR VALU, no conflicts.
// Mask init rewritten as (sext-bitfield & bits(-1e9)) = 2 VALU/elem
// (fuses to v_bfe_i32 + v_and) replacing and/cmp/cndmask chains.

typedef __attribute__((ext_vector_type(8))) short bf16x8;
typedef __attribute__((ext_vector_type(16))) float f32x16;

#define NEGV (-1e9f)
#define NEGBITS 0xCE6E6B28u    // bit pattern of -1e9f

__device__ inline unsigned cvt_bf16(float f) {
    unsigned u = __builtin_bit_cast(unsigned, f);
    u += 0x7FFFu + ((u >> 16) & 1u);   // RNE
    return u >> 16;
}
__device__ inline unsigned pk_bf16(float a, float b) {       // RNE pack (Q prologue only)
    return cvt_bf16(a) | (cvt_bf16(b) << 16);
}
__device__ inline unsigned pk_trunc(float a, float b) {      // 1 v_perm_b32
    return __builtin_amdgcn_perm(__builtin_bit_cast(unsigned, b),
                                 __builtin_bit_cast(unsigned, a), 0x07060302u);
}

#define WS_KV_OFF  2097152u                 // 2 MB for bitT
#define WS_NEED    39845888ull              // 2 MB + 2048 tiles * 18432 B

// ---- fused pre-kernel ----
// blocks [0,2048):     mask int32 [b][q][kk] -> bit-words bitT[b][qt][ki][q]
// blocks [2048,6144):  K f32 -> bf16 tile images, pitch 144B (8 chunks + pad)
// blocks [6144,10240): V f32 -> V^T bf16 tile images, pitch 144B
// KV layout: tile (bh*32+ki) occupies 18432B: K-image rows r=0..63 at
// r*144 (128B data), then V^T-image rows d=0..63 at 9216 + d*144.
__global__ __launch_bounds__(256)
void preconv(const int* __restrict__ M, const float* __restrict__ K,
             const float* __restrict__ V, unsigned long long* __restrict__ bitT,
             unsigned short* __restrict__ KV) {
    const int tid  = threadIdx.x;
    const int lane = tid & 63;
    const int bid  = blockIdx.x;

    if (bid < 2048) {                       // ---- mask pack ----
        const int gw = (bid * 256 + tid) >> 6;      // row id 0..8191
        const int b  = gw >> 11;
        const int qt = (gw >> 8) & 7;
        const int q  = gw & 255;
        const size_t mbase = (size_t)gw * 2048;
        unsigned long long* dst = bitT + (size_t)(b * 8 + qt) * 32 * 256 + q;
#pragma unroll 4
        for (int ki = 0; ki < 32; ki++) {
            const int m = M[mbase + ki * 64 + lane];
            const unsigned long long bal = __ballot(m != 0);
            if (lane == 0) dst[ki * 256] = bal;
        }
    } else if (bid < 6144) {                // ---- K convert: 1 16B chunk / thread ----
        const unsigned g   = (unsigned)(bid - 2048) * 256 + tid;   // 0..1048575
        const int c        = g & 7;
        const unsigned rid = g >> 3;         // bh*2048 + ki*64 + r
        const int r        = rid & 63;
        const unsigned tile = rid >> 6;      // bh*32 + ki
        const float* src = K + (size_t)rid * 64 + c * 8;
        const float4 f0 = *(const float4*)(src);
        const float4 f1 = *(const float4*)(src + 4);
        uint4 p;
        p.x = pk_trunc(f0.x, f0.y); p.y = pk_trunc(f0.z, f0.w);
        p.z = pk_trunc(f1.x, f1.y); p.w = pk_trunc(f1.z, f1.w);
        *(uint4*)&KV[(size_t)tile * 9216 + r * 72 + c * 8] = p;
    } else {                                // ---- V^T convert: 1 16B chunk / thread ----
        const unsigned g = (unsigned)(bid - 6144) * 256 + tid;     // 0..1048575
        const int d  = g & 63;
        const int c  = (g >> 6) & 7;
        const int ki = (g >> 9) & 31;
        const int bh = g >> 14;
        const float* src = V + ((size_t)(bh * 2048 + ki * 64 + c * 8) * 64 + d);
        float v[8];
#pragma unroll
        for (int j = 0; j < 8; j++) v[j] = src[j * 64];
        uint4 p;
        p.x = pk_trunc(v[0], v[1]); p.y = pk_trunc(v[2], v[3]);
        p.z = pk_trunc(v[4], v[5]); p.w = pk_trunc(v[6], v[7]);
        *(uint4*)&KV[(size_t)(bh * 32 + ki) * 9216 + 4608 + d * 72 + c * 8] = p;
    }
}

// ---- fast attention: linear staging of pre-padded pitch-144 tile images ----
__global__ __launch_bounds__(256, 4)
void attn_fast(const float* __restrict__ Q,
               const unsigned short* __restrict__ KV,
               const unsigned long long* __restrict__ bitT,
               float* __restrict__ Out) {
    __shared__ __attribute__((aligned(16))) unsigned short sT[2][9216];  // 18 KB x2
    // total 36.9 KB -> 4 blocks/CU (147.5/160 KB)

    const int tid  = threadIdx.x;
    const int wave = tid >> 6;
    const int lane = tid & 63;
    const int half = lane >> 5;
    const int l32  = lane & 31;

    const int bid = blockIdx.x;
    const int h   = bid & 15;
    const int qt2 = (bid >> 4) & 15;
    const int b   = bid >> 8;
    const int bh  = b * 16 + h;
    const int q0  = qt2 * 128;
    const int qt  = qt2 >> 1;
    const int qh  = qt2 & 1;

    const float* Qb = Q + (size_t)(bh * 2048 + q0) * 64;
    const unsigned short* Tg = KV + (size_t)bh * 32 * 9216;   // this bh's 32 tiles
    const unsigned long long* Bt = bitT + (size_t)(b * 8 + qt) * 32 * 256
                                 + qh * 128 + wave * 32 + l32;

    // ---- stage tile ki (18432B image) into sT[buf]: 4x16B + 2x4B per thread ----
    #define STAGE(buf, ki) do {                                                   \
        const unsigned short* g_ = Tg + (size_t)(ki) * 9216;                      \
        unsigned short* l_ = sT[buf];                                             \
        _Pragma("unroll")                                                         \
        for (int q_ = 0; q_ < 4; q_++)                                            \
            __builtin_amdgcn_global_load_lds(                                     \
                (const __attribute__((address_space(1))) void*)                   \
                    (g_ + q_ * 2048 + wave * 512 + lane * 8),                     \
                (__attribute__((address_space(3))) void*)                         \
                    (l_ + q_ * 2048 + wave * 512), 16, 0, 0);                     \
        _Pragma("unroll")                                                         \
        for (int s_ = 0; s_ < 2; s_++)                                            \
            __builtin_amdgcn_global_load_lds(                                     \
                (const __attribute__((address_space(1))) void*)                   \
                    (g_ + 8192 + s_ * 512 + wave * 128 + lane * 2),               \
                (__attribute__((address_space(3))) void*)                         \
                    (l_ + 8192 + s_ * 512 + wave * 128), 4, 0, 0);                \
    } while (0)

    STAGE(0, 0);
    unsigned long long mw = Bt[0];

    // ---- Q fragments (pre-scaled by 1/8), RNE, live all kernel ----
    bf16x8 qF[4];
    {
        const float* qr = Qb + (size_t)(wave * 32 + l32) * 64 + half * 8;
#pragma unroll
        for (int dk = 0; dk < 4; dk++) {
            const float4 f0 = *(const float4*)(qr + dk * 16);
            const float4 f1 = *(const float4*)(qr + dk * 16 + 4);
            union { bf16x8 v; unsigned u[4]; } t;
            t.u[0] = pk_bf16(f0.x * 0.125f, f0.y * 0.125f);
            t.u[1] = pk_bf16(f0.z * 0.125f, f0.w * 0.125f);
            t.u[2] = pk_bf16(f1.x * 0.125f, f1.y * 0.125f);
            t.u[3] = pk_bf16(f1.z * 0.125f, f1.w * 0.125f);
            qF[dk] = t.v;
        }
    }

    f32x16 Oacc[2];
#pragma unroll
    for (int db = 0; db < 2; db++)
#pragma unroll
        for (int r = 0; r < 16; r++) Oacc[db][r] = 0.f;

    __syncthreads();   // drains tile-0 stage + all waves arrived

    for (int ki = 0; ki < 32; ki++) {
        const int cur = ki & 1;

        // issue next tile's stage + mask prefetch; drained by end-of-iter barrier
        unsigned long long mwN = 0;
        if (ki < 31) {
            STAGE(cur ^ 1, ki + 1);
            mwN = Bt[(ki + 1) * 256];
        }

#pragma unroll
        for (int jk = 0; jk < 2; jk++) {
            bf16x8 aK[4];
#pragma unroll
            for (int dk = 0; dk < 4; dk++)
                aK[dk] = *(const bf16x8*)&sT[cur][(jk * 32 + l32) * 72 + dk * 16 + half * 8];
            bf16x8 bV[2][2];
#pragma unroll
            for (int p = 0; p < 2; p++)
#pragma unroll
                for (int db = 0; db < 2; db++)
                    bV[p][db] = *(const bf16x8*)&sT[cur][4608 + (db * 32 + l32) * 72
                                                         + (jk * 2 + p) * 16 + half * 8];

            // bit for acc[rg*4+w] = jk*32 + rg*8 + half*4 + w  (q = l32's row word)
            const unsigned b32 = (unsigned)(mw >> (jk * 32));
            const unsigned bsh = b32 >> (half * 4);

            // masked init: sext(bit) & bits(-1e9) -> v_bfe_i32 + v_and (2 ops/elem).
            // -1e9 + qk trunc-packs to EXACTLY bf16(-1e9) (ulp@2^29=64 absorbs qk).
            f32x16 acc;
#pragma unroll
            for (int rg = 0; rg < 4; rg++) {
#pragma unroll
                for (int w = 0; w < 4; w++) {
                    const int pos = rg * 8 + w;
                    const int sb = ((int)(bsh << (31 - pos))) >> 31;   // 0 or -1
                    acc[rg * 4 + w] = __builtin_bit_cast(float, (unsigned)sb & NEGBITS);
                }
            }
#pragma unroll
            for (int dk = 0; dk < 4; dk++)
                acc = __builtin_amdgcn_mfma_f32_32x32x16_bf16(aK[dk], qF[dk], acc, 0, 0, 0);

            // acc[r] holds S[q=l32][kk32 = (r&3) + 8*(r>>2) + 4*half].
            // in-register S^T -> S transpose via permlane32_swap (HK T12):
            //   (P0,P2) -> (word j=0,1 ; word j=4,5); (P1,P3) -> (j=2,3 ; j=6,7)
#pragma unroll
            for (int p = 0; p < 2; p++) {
                const unsigned P0 = pk_trunc(acc[p * 8 + 0], acc[p * 8 + 1]);
                const unsigned P1 = pk_trunc(acc[p * 8 + 2], acc[p * 8 + 3]);
                const unsigned P2 = pk_trunc(acc[p * 8 + 4], acc[p * 8 + 5]);
                const unsigned P3 = pk_trunc(acc[p * 8 + 6], acc[p * 8 + 7]);
                auto r02 = __builtin_amdgcn_permlane32_swap(P0, P2, false, false);
                auto r13 = __builtin_amdgcn_permlane32_swap(P1, P3, false, false);
                union { bf16x8 v; unsigned u[4]; } aS;
                aS.u[0] = (unsigned)r02[0];
                aS.u[1] = (unsigned)r13[0];
                aS.u[2] = (unsigned)r02[1];
                aS.u[3] = (unsigned)r13[1];
#pragma unroll
                for (int db = 0; db < 2; db++)
                    Oacc[db] = __builtin_amdgcn_mfma_f32_32x32x16_bf16(aS.v, bV[p][db], Oacc[db], 0, 0, 0);
            }
        }

        mw = mwN;
        __syncthreads();   // drains next-tile stage; protects buf reuse
    }

    // ---- epilogue: log_softmax over d=64 ----
    float* Ob = Out + (size_t)bh * 2048 * 64;
#pragma unroll
    for (int r = 0; r < 16; r++) {
        const float v0 = Oacc[0][r], v1 = Oacc[1][r];
        float mx = fmaxf(v0, v1);
#pragma unroll
        for (int off = 1; off < 32; off <<= 1)
            mx = fmaxf(mx, __shfl_xor(mx, off, 64));
        float s = __expf(v0 - mx) + __expf(v1 - mx);
#pragma unroll
        for (int off = 1; off < 32; off <<= 1)
            s += __shfl_xor(s, off, 64);
        const float lse = mx + __logf(s);
        const int qrow = q0 + wave * 32 + (r & 3) + 8 * (r >> 2) + 4 * half;
        Ob[(size_t)qrow * 64 + l32]      = v0 - lse;
        Ob[(size_t)qrow * 64 + 32 + l32] = v1 - lse;
    }
    #undef STAGE
}

// ================= fallback path (exact v10) =================
__global__ __launch_bounds__(256)
void mask_pack(const int* __restrict__ M, unsigned long long* __restrict__ bitT) {
    const int lane = threadIdx.x & 63;
    const int gw   = (blockIdx.x * 256 + threadIdx.x) >> 6;
    const int b    = gw >> 11;
    const int qt   = (gw >> 8) & 7;
    const int q    = gw & 255;
    const size_t mbase = (size_t)gw * 2048;
    unsigned long long* dst = bitT + (size_t)(b * 8 + qt) * 32 * 256 + q;
#pragma unroll 4
    for (int ki = 0; ki < 32; ki++) {
        const int m = M[mbase + ki * 64 + lane];
        const unsigned long long bal = __ballot(m != 0);
        if (lane == 0) dst[ki * 256] = bal;
    }
}

__global__ __launch_bounds__(256, 4)
void attn_v10(const float* __restrict__ Q, const float* __restrict__ K,
              const float* __restrict__ V,
              const unsigned long long* __restrict__ bitT,
              float* __restrict__ Out) {
    __shared__ __attribute__((aligned(16))) unsigned short sK[2][64 * 72];
    __shared__ __attribute__((aligned(16))) unsigned short sVt[2][64 * 72];

    const int tid  = threadIdx.x;
    const int wave = tid >> 6;
    const int lane = tid & 63;
    const int half = lane >> 5;
    const int l32  = lane & 31;

    const int bid = blockIdx.x;
    const int h   = bid & 15;
    const int qt2 = (bid >> 4) & 15;
    const int b   = bid >> 8;
    const int bh  = b * 16 + h;
    const int q0  = qt2 * 128;
    const int qt  = qt2 >> 1;
    const int qh  = qt2 & 1;

    const float* Qb = Q + (size_t)(bh * 2048 + q0) * 64;
    const float* Kb = K + (size_t)bh * 2048 * 64;
    const float* Vb = V + (size_t)bh * 2048 * 64;
    const unsigned long long* Bt = bitT + (size_t)(b * 8 + qt) * 32 * 256
                                 + qh * 128 + wave * 32 + l32;

    float4 kp[4];
    float  vp[16];
    unsigned long long mw = Bt[0];
    const int krow = tid >> 4, kc4 = tid & 15;
#pragma unroll
    for (int i = 0; i < 4; i++)
        kp[i] = *(const float4*)(Kb + (size_t)(krow + i * 16) * 64 + kc4 * 4);
#pragma unroll
    for (int i = 0; i < 2; i++) {
        const int kb = (wave * 2 + i) * 8;
#pragma unroll
        for (int j = 0; j < 8; j++)
            vp[i * 8 + j] = Vb[(size_t)(kb + j) * 64 + lane];
    }

    bf16x8 qF[4];
    {
        const float* qr = Qb + (size_t)(wave * 32 + l32) * 64 + half * 8;
#pragma unroll
        for (int dk = 0; dk < 4; dk++) {
            const float4 f0 = *(const float4*)(qr + dk * 16);
            const float4 f1 = *(const float4*)(qr + dk * 16 + 4);
            union { bf16x8 v; unsigned u[4]; } t;
            t.u[0] = pk_bf16(f0.x * 0.125f, f0.y * 0.125f);
            t.u[1] = pk_bf16(f0.z * 0.125f, f0.w * 0.125f);
            t.u[2] = pk_bf16(f1.x * 0.125f, f1.y * 0.125f);
            t.u[3] = pk_bf16(f1.z * 0.125f, f1.w * 0.125f);
            qF[dk] = t.v;
        }
    }

    f32x16 Oacc[2];
#pragma unroll
    for (int db = 0; db < 2; db++)
#pragma unroll
        for (int r = 0; r < 16; r++) Oacc[db][r] = 0.f;

    for (int ki = 0; ki < 32; ki++) {
        const int cur = ki & 1;
#pragma unroll
        for (int i = 0; i < 4; i++) {
            uint2 p;
            p.x = pk_trunc(kp[i].x, kp[i].y);
            p.y = pk_trunc(kp[i].z, kp[i].w);
            *(uint2*)&sK[cur][(krow + i * 16) * 72 + kc4 * 4] = p;
        }
#pragma unroll
        for (int i = 0; i < 2; i++) {
            const int kb = (wave * 2 + i) * 8;
            uint4 p4;
            p4.x = pk_trunc(vp[i * 8 + 0], vp[i * 8 + 1]);
            p4.y = pk_trunc(vp[i * 8 + 2], vp[i * 8 + 3]);
            p4.z = pk_trunc(vp[i * 8 + 4], vp[i * 8 + 5]);
            p4.w = pk_trunc(vp[i * 8 + 6], vp[i * 8 + 7]);
            *(uint4*)&sVt[cur][lane * 72 + kb] = p4;
        }

        __syncthreads();

        unsigned long long mwN = 0;
        if (ki < 31) {
            const int kn = (ki + 1) * 64;
            mwN = Bt[(ki + 1) * 256];
#pragma unroll
            for (int i = 0; i < 4; i++)
                kp[i] = *(const float4*)(Kb + (size_t)(kn + krow + i * 16) * 64 + kc4 * 4);
#pragma unroll
            for (int i = 0; i < 2; i++) {
                const int kb = (wave * 2 + i) * 8;
#pragma unroll
                for (int j = 0; j < 8; j++)
                    vp[i * 8 + j] = Vb[(size_t)(kn + kb + j) * 64 + lane];
            }
        }

#pragma unroll
        for (int jk = 0; jk < 2; jk++) {
            bf16x8 aK[4];
#pragma unroll
            for (int dk = 0; dk < 4; dk++)
                aK[dk] = *(const bf16x8*)&sK[cur][(jk * 32 + l32) * 72 + dk * 16 + half * 8];
            bf16x8 bV[2][2];
#pragma unroll
            for (int p = 0; p < 2; p++)
#pragma unroll
                for (int db = 0; db < 2; db++)
                    bV[p][db] = *(const bf16x8*)&sVt[cur][(db * 32 + l32) * 72 + (jk * 2 + p) * 16 + half * 8];

            const unsigned b32 = (unsigned)(mw >> (jk * 32));
            const unsigned bsh = b32 >> (half * 4);

            f32x16 acc;
#pragma unroll
            for (int rg = 0; rg < 4; rg++) {
                const unsigned nib = bsh >> (rg * 8);
                acc[rg * 4 + 0] = (nib & 1u) ? NEGV : 0.f;
                acc[rg * 4 + 1] = (nib & 2u) ? NEGV : 0.f;
                acc[rg * 4 + 2] = (nib & 4u) ? NEGV : 0.f;
                acc[rg * 4 + 3] = (nib & 8u) ? NEGV : 0.f;
            }
#pragma unroll
            for (int dk = 0; dk < 4; dk++)
                acc = __builtin_amdgcn_mfma_f32_32x32x16_bf16(aK[dk], qF[dk], acc, 0, 0, 0);

#pragma unroll
            for (int p = 0; p < 2; p++) {
                const unsigned P0 = pk_trunc(acc[p * 8 + 0], acc[p * 8 + 1]);
                const unsigned P1 = pk_trunc(acc[p * 8 + 2], acc[p * 8 + 3]);
                const unsigned P2 = pk_trunc(acc[p * 8 + 4], acc[p * 8 + 5]);
                const unsigned P3 = pk_trunc(acc[p * 8 + 6], acc[p * 8 + 7]);
                auto r02 = __builtin_amdgcn_permlane32_swap(P0, P2, false, false);
                auto r13 = __builtin_amdgcn_permlane32_swap(P1, P3, false, false);
                union { bf16x8 v; unsigned u[4]; } aS;
                aS.u[0] = (unsigned)r02[0];
                aS.u[1] = (unsigned)r13[0];
                aS.u[2] = (unsigned)r02[1];
                aS.u[3] = (unsigned)r13[1];
#pragma unroll
                for (int db = 0; db < 2; db++)
                    Oacc[db] = __builtin_amdgcn_mfma_f32_32x32x16_bf16(aS.v, bV[p][db], Oacc[db], 0, 0, 0);
            }
        }

        mw = mwN;
    }

    float* Ob = Out + (size_t)bh * 2048 * 64;
#pragma unroll
    for (int r = 0; r < 16; r++) {
        const float v0 = Oacc[0][r], v1 = Oacc[1][r];
        float mx = fmaxf(v0, v1);
#pragma unroll
        for (int off = 1; off < 32; off <<= 1)
            mx = fmaxf(mx, __shfl_xor(mx, off, 64));
        float s = __expf(v0 - mx) + __expf(v1 - mx);
#pragma unroll
        for (int off = 1; off < 32; off <<= 1)
            s += __shfl_xor(s, off, 64);
        const float lse = mx + __logf(s);
        const int qrow = q0 + wave * 32 + (r & 3) + 8 * (r >> 2) + 4 * half;
        Ob[(size_t)qrow * 64 + l32]      = v0 - lse;
        Ob[(size_t)qrow * 64 + 32 + l32] = v1 - lse;
    }
}

extern "C" void kernel_launch(void* const* d_in, const int* in_sizes, int n_in,
                              void* d_out, int out_size, void* d_ws, size_t ws_size,
                              hipStream_t stream) {
    const float* Q = (const float*)d_in[0];
    const float* K = (const float*)d_in[1];
    const float* V = (const float*)d_in[2];
    const int*   M = (const int*)d_in[3];
    float* Out = (float*)d_out;
    unsigned long long* bitT = (unsigned long long*)d_ws;

    if (ws_size >= WS_NEED) {
        unsigned short* KV = (unsigned short*)((char*)d_ws + WS_KV_OFF);
        preconv<<<dim3(10240), dim3(256), 0, stream>>>(M, K, V, bitT, KV);
        attn_fast<<<dim3(1024), dim3(256), 0, stream>>>(Q, KV, bitT, Out);
    } else {
        mask_pack<<<dim3(2048), dim3(256), 0, stream>>>(M, bitT);
        attn_v10<<<dim3(1024), dim3(256), 0, stream>>>(Q, K, V, bitT, Out);
    }
}

// Round 8
// 268.060 us; speedup vs baseline: 1.0317x; 1.0317x over previous
//
#include <hip/hip_runtime.h>
#include <hip/hip_bf16.h>

// B=4, H=16, S=2048, D=64
//   S = mask ? -1e9 : QK^T/8 ; O = S@V ; out = log_softmax(O, dim=-1)
// v13: v12's profile shows load latency fully hidden (7000-cyc cover vs
// 900-cyc HBM) — the residual ~24% stall is the per-iter barrier convoy,
// which exists only for the LDS handoff. KV per bh (512KB bf16) is
// L2-resident and shared by 16 same-XCD blocks => LDS staging is overhead
// (guide m169). preconv now emits K/V in EXACT MFMA-fragment order
// (16B/lane chunks) via an LDS-bounce (coalesced reads AND writes); attn
// reads fragments directly with coalesced global_load_dwordx4 from L2.
// No LDS, no barriers, no staging in attn — waves fully independent.

typedef __attribute__((ext_vector_type(8))) short bf16x8;
typedef __attribute__((ext_vector_type(16))) float f32x16;

#define NEGV (-1e9f)
#define NEGBITS 0xCE6E6B28u    // bit pattern of -1e9f

__device__ inline unsigned cvt_bf16(float f) {
    unsigned u = __builtin_bit_cast(unsigned, f);
    u += 0x7FFFu + ((u >> 16) & 1u);   // RNE
    return u >> 16;
}
__device__ inline unsigned pk_bf16(float a, float b) {       // RNE pack (Q prologue only)
    return cvt_bf16(a) | (cvt_bf16(b) << 16);
}
__device__ inline unsigned pk_trunc(float a, float b) {      // 1 v_perm_b32
    return __builtin_amdgcn_perm(__builtin_bit_cast(unsigned, b),
                                 __builtin_bit_cast(unsigned, a), 0x07060302u);
}

#define WS_KV_OFF 2097152u                              // 2 MB for bitT
#define WS_NEED   (2097152ull + 2048ull * 16384ull)     // + 2048 tiles * 16 KB

// ---- fused pre-kernel ----
// blocks [0,2048):    mask int32 [b][q][kk] -> bit-words bitT[b][qt][ki][q]
// blocks [2048,4096): one (bh,ki) tile per block -> fragment images:
//   KF chunk kc=(jk*4+dk)*64+lane (16B): K[ki*64+jk*32+(lane&31)]
//                                         [dk*16+(lane>>5)*8 .. +7]  (bf16)
//   VF chunk vc=((jk2)*2+db)*64+lane (16B): V[ki*64+jk2*16+(lane>>5)*8+j]
//                                            [db*32+(lane&31)], j=0..7
// tile image = 8KB KF + 8KB VF at KV + tile*16384B.
__global__ __launch_bounds__(256)
void preconv(const int* __restrict__ M, const float* __restrict__ K,
             const float* __restrict__ V, unsigned long long* __restrict__ bitT,
             unsigned short* __restrict__ KV) {
    const int tid  = threadIdx.x;
    const int lane = tid & 63;
    const int bid  = blockIdx.x;

    if (bid < 2048) {                       // ---- mask pack ----
        const int gw = (bid * 256 + tid) >> 6;      // row id 0..8191
        const int b  = gw >> 11;
        const int qt = (gw >> 8) & 7;
        const int q  = gw & 255;
        const size_t mbase = (size_t)gw * 2048;
        unsigned long long* dst = bitT + (size_t)(b * 8 + qt) * 32 * 256 + q;
#pragma unroll 4
        for (int ki = 0; ki < 32; ki++) {
            const int m = M[mbase + ki * 64 + lane];
            const unsigned long long bal = __ballot(m != 0);
            if (lane == 0) dst[ki * 256] = bal;
        }
        return;
    }

    // ---- tile fragment builder ----
    __shared__ float sF[64][68];            // 17.4 KB, padded
    const int tile = bid - 2048;            // bh*32 + ki
    const float* Ksrc = K + (size_t)tile * 64 * 64;   // (bh*2048 + ki*64)*64
    const float* Vsrc = V + (size_t)tile * 64 * 64;
    unsigned short* KF = KV + (size_t)tile * 8192;    // shorts
    unsigned short* VF = KF + 4096;

    // K tile -> LDS (coalesced)
#pragma unroll
    for (int k = 0; k < 4; k++) {
        const int f = tid + k * 256;        // float4 id
        const int row = f >> 4, c4 = f & 15;
        *(float4*)&sF[row][c4 * 4] = *(const float4*)(Ksrc + row * 64 + c4 * 4);
    }
    __syncthreads();
    // emit KF (coalesced 16B writes)
#pragma unroll
    for (int k = 0; k < 2; k++) {
        const int kc = tid + k * 256;
        const int jk = kc >> 8, dk = (kc >> 6) & 3, ln = kc & 63;
        const int r  = jk * 32 + (ln & 31);
        const int e0 = dk * 16 + (ln >> 5) * 8;
        const float* s = &sF[r][e0];
        uint4 p;
        p.x = pk_trunc(s[0], s[1]); p.y = pk_trunc(s[2], s[3]);
        p.z = pk_trunc(s[4], s[5]); p.w = pk_trunc(s[6], s[7]);
        *(uint4*)&KF[kc * 8] = p;
    }
    __syncthreads();
    // V tile -> LDS [kk][d] (coalesced)
#pragma unroll
    for (int k = 0; k < 4; k++) {
        const int f = tid + k * 256;
        const int row = f >> 4, c4 = f & 15;
        *(float4*)&sF[row][c4 * 4] = *(const float4*)(Vsrc + row * 64 + c4 * 4);
    }
    __syncthreads();
    // emit VF (coalesced 16B writes; LDS column reads)
#pragma unroll
    for (int k = 0; k < 2; k++) {
        const int vc  = tid + k * 256;
        const int jk2 = vc >> 7, db = (vc >> 6) & 1, ln = vc & 63;
        const int d   = db * 32 + (ln & 31);
        const int kk0 = jk2 * 16 + (ln >> 5) * 8;
        float v[8];
#pragma unroll
        for (int j = 0; j < 8; j++) v[j] = sF[kk0 + j][d];
        uint4 p;
        p.x = pk_trunc(v[0], v[1]); p.y = pk_trunc(v[2], v[3]);
        p.z = pk_trunc(v[4], v[5]); p.w = pk_trunc(v[6], v[7]);
        *(uint4*)&VF[vc * 8] = p;
    }
}

// ---- fast attention: barrier-free, LDS-free, direct L2 fragment loads ----
__global__ __launch_bounds__(256, 4)
void attn_fast(const float* __restrict__ Q,
               const unsigned short* __restrict__ KV,
               const unsigned long long* __restrict__ bitT,
               float* __restrict__ Out) {
    const int tid  = threadIdx.x;
    const int wave = tid >> 6;
    const int lane = tid & 63;
    const int half = lane >> 5;
    const int l32  = lane & 31;

    const int bid = blockIdx.x;
    const int h   = bid & 15;
    const int qt2 = (bid >> 4) & 15;
    const int b   = bid >> 8;
    const int bh  = b * 16 + h;
    const int q0  = qt2 * 128;
    const int qt  = qt2 >> 1;
    const int qh  = qt2 & 1;

    const float* Qb = Q + (size_t)(bh * 2048 + q0) * 64;
    const unsigned short* Tg = KV + (size_t)bh * 32 * 8192;   // shorts
    const unsigned long long* Bt = bitT + (size_t)(b * 8 + qt) * 32 * 256
                                 + qh * 128 + wave * 32 + l32;

    // ---- Q fragments (pre-scaled by 1/8), RNE, live all kernel ----
    bf16x8 qF[4];
    {
        const float* qr = Qb + (size_t)(wave * 32 + l32) * 64 + half * 8;
#pragma unroll
        for (int dk = 0; dk < 4; dk++) {
            const float4 f0 = *(const float4*)(qr + dk * 16);
            const float4 f1 = *(const float4*)(qr + dk * 16 + 4);
            union { bf16x8 v; unsigned u[4]; } t;
            t.u[0] = pk_bf16(f0.x * 0.125f, f0.y * 0.125f);
            t.u[1] = pk_bf16(f0.z * 0.125f, f0.w * 0.125f);
            t.u[2] = pk_bf16(f1.x * 0.125f, f1.y * 0.125f);
            t.u[3] = pk_bf16(f1.z * 0.125f, f1.w * 0.125f);
            qF[dk] = t.v;
        }
    }

    f32x16 Oacc[2];
#pragma unroll
    for (int db = 0; db < 2; db++)
#pragma unroll
        for (int r = 0; r < 16; r++) Oacc[db][r] = 0.f;

    unsigned long long mw = Bt[0];

    for (int ki = 0; ki < 32; ki++) {
        const unsigned short* T = Tg + ki * 8192;
        const unsigned long long mwN = (ki < 31) ? Bt[(ki + 1) * 256] : 0ull;

#pragma unroll
        for (int jk = 0; jk < 2; jk++) {
            // fragment loads: coalesced 16B/lane straight from L2
            bf16x8 aK[4];
#pragma unroll
            for (int dk = 0; dk < 4; dk++)
                aK[dk] = *(const bf16x8*)(T + ((jk * 4 + dk) * 64 + lane) * 8);
            bf16x8 bV[2][2];
#pragma unroll
            for (int p = 0; p < 2; p++)
#pragma unroll
                for (int db = 0; db < 2; db++)
                    bV[p][db] = *(const bf16x8*)(T + 4096 +
                        (((jk * 2 + p) * 2 + db) * 64 + lane) * 8);

            // bit for acc[rg*4+w] = jk*32 + rg*8 + half*4 + w (q = l32's row word)
            const unsigned b32 = (unsigned)(mw >> (jk * 32));
            const unsigned bsh = b32 >> (half * 4);

            // masked init: sext(bit) & bits(-1e9) -> v_bfe_i32 + v_and.
            // -1e9 + qk trunc-packs to EXACTLY bf16(-1e9) (ulp@2^29=64).
            f32x16 acc;
#pragma unroll
            for (int rg = 0; rg < 4; rg++) {
#pragma unroll
                for (int w = 0; w < 4; w++) {
                    const int pos = rg * 8 + w;
                    const int sb = ((int)(bsh << (31 - pos))) >> 31;   // 0 or -1
                    acc[rg * 4 + w] = __builtin_bit_cast(float, (unsigned)sb & NEGBITS);
                }
            }
#pragma unroll
            for (int dk = 0; dk < 4; dk++)
                acc = __builtin_amdgcn_mfma_f32_32x32x16_bf16(aK[dk], qF[dk], acc, 0, 0, 0);

            // acc[r] holds S[q=l32][kk32 = (r&3) + 8*(r>>2) + 4*half].
            // in-register S^T -> S transpose via permlane32_swap (HK T12):
            //   (P0,P2) -> (word j=0,1 ; word j=4,5); (P1,P3) -> (j=2,3 ; j=6,7)
#pragma unroll
            for (int p = 0; p < 2; p++) {
                const unsigned P0 = pk_trunc(acc[p * 8 + 0], acc[p * 8 + 1]);
                const unsigned P1 = pk_trunc(acc[p * 8 + 2], acc[p * 8 + 3]);
                const unsigned P2 = pk_trunc(acc[p * 8 + 4], acc[p * 8 + 5]);
                const unsigned P3 = pk_trunc(acc[p * 8 + 6], acc[p * 8 + 7]);
                auto r02 = __builtin_amdgcn_permlane32_swap(P0, P2, false, false);
                auto r13 = __builtin_amdgcn_permlane32_swap(P1, P3, false, false);
                union { bf16x8 v; unsigned u[4]; } aS;
                aS.u[0] = (unsigned)r02[0];
                aS.u[1] = (unsigned)r13[0];
                aS.u[2] = (unsigned)r02[1];
                aS.u[3] = (unsigned)r13[1];
#pragma unroll
                for (int db = 0; db < 2; db++)
                    Oacc[db] = __builtin_amdgcn_mfma_f32_32x32x16_bf16(aS.v, bV[p][db], Oacc[db], 0, 0, 0);
            }
        }

        mw = mwN;
    }

    // ---- epilogue: log_softmax over d=64 ----
    float* Ob = Out + (size_t)bh * 2048 * 64;
#pragma unroll
    for (int r = 0; r < 16; r++) {
        const float v0 = Oacc[0][r], v1 = Oacc[1][r];
        float mx = fmaxf(v0, v1);
#pragma unroll
        for (int off = 1; off < 32; off <<= 1)
            mx = fmaxf(mx, __shfl_xor(mx, off, 64));
        float s = __expf(v0 - mx) + __expf(v1 - mx);
#pragma unroll
        for (int off = 1; off < 32; off <<= 1)
            s += __shfl_xor(s, off, 64);
        const float lse = mx + __logf(s);
        const int qrow = q0 + wave * 32 + (r & 3) + 8 * (r >> 2) + 4 * half;
        Ob[(size_t)qrow * 64 + l32]      = v0 - lse;
        Ob[(size_t)qrow * 64 + 32 + l32] = v1 - lse;
    }
}

// ================= fallback path (exact v10) =================
__global__ __launch_bounds__(256)
void mask_pack(const int* __restrict__ M, unsigned long long* __restrict__ bitT) {
    const int lane = threadIdx.x & 63;
    const int gw   = (blockIdx.x * 256 + threadIdx.x) >> 6;
    const int b    = gw >> 11;
    const int qt   = (gw >> 8) & 7;
    const int q    = gw & 255;
    const size_t mbase = (size_t)gw * 2048;
    unsigned long long* dst = bitT + (size_t)(b * 8 + qt) * 32 * 256 + q;
#pragma unroll 4
    for (int ki = 0; ki < 32; ki++) {
        const int m = M[mbase + ki * 64 + lane];
        const unsigned long long bal = __ballot(m != 0);
        if (lane == 0) dst[ki * 256] = bal;
    }
}

__global__ __launch_bounds__(256, 4)
void attn_v10(const float* __restrict__ Q, const float* __restrict__ K,
              const float* __restrict__ V,
              const unsigned long long* __restrict__ bitT,
              float* __restrict__ Out) {
    __shared__ __attribute__((aligned(16))) unsigned short sK[2][64 * 72];
    __shared__ __attribute__((aligned(16))) unsigned short sVt[2][64 * 72];

    const int tid  = threadIdx.x;
    const int wave = tid >> 6;
    const int lane = tid & 63;
    const int half = lane >> 5;
    const int l32  = lane & 31;

    const int bid = blockIdx.x;
    const int h   = bid & 15;
    const int qt2 = (bid >> 4) & 15;
    const int b   = bid >> 8;
    const int bh  = b * 16 + h;
    const int q0  = qt2 * 128;
    const int qt  = qt2 >> 1;
    const int qh  = qt2 & 1;

    const float* Qb = Q + (size_t)(bh * 2048 + q0) * 64;
    const float* Kb = K + (size_t)bh * 2048 * 64;
    const float* Vb = V + (size_t)bh * 2048 * 64;
    const unsigned long long* Bt = bitT + (size_t)(b * 8 + qt) * 32 * 256
                                 + qh * 128 + wave * 32 + l32;

    float4 kp[4];
    float  vp[16];
    unsigned long long mw = Bt[0];
    const int krow = tid >> 4, kc4 = tid & 15;
#pragma unroll
    for (int i = 0; i < 4; i++)
        kp[i] = *(const float4*)(Kb + (size_t)(krow + i * 16) * 64 + kc4 * 4);
#pragma unroll
    for (int i = 0; i < 2; i++) {
        const int kb = (wave * 2 + i) * 8;
#pragma unroll
        for (int j = 0; j < 8; j++)
            vp[i * 8 + j] = Vb[(size_t)(kb + j) * 64 + lane];
    }

    bf16x8 qF[4];
    {
        const float* qr = Qb + (size_t)(wave * 32 + l32) * 64 + half * 8;
#pragma unroll
        for (int dk = 0; dk < 4; dk++) {
            const float4 f0 = *(const float4*)(qr + dk * 16);
            const float4 f1 = *(const float4*)(qr + dk * 16 + 4);
            union { bf16x8 v; unsigned u[4]; } t;
            t.u[0] = pk_bf16(f0.x * 0.125f, f0.y * 0.125f);
            t.u[1] = pk_bf16(f0.z * 0.125f, f0.w * 0.125f);
            t.u[2] = pk_bf16(f1.x * 0.125f, f1.y * 0.125f);
            t.u[3] = pk_bf16(f1.z * 0.125f, f1.w * 0.125f);
            qF[dk] = t.v;
        }
    }

    f32x16 Oacc[2];
#pragma unroll
    for (int db = 0; db < 2; db++)
#pragma unroll
        for (int r = 0; r < 16; r++) Oacc[db][r] = 0.f;

    for (int ki = 0; ki < 32; ki++) {
        const int cur = ki & 1;
#pragma unroll
        for (int i = 0; i < 4; i++) {
            uint2 p;
            p.x = pk_trunc(kp[i].x, kp[i].y);
            p.y = pk_trunc(kp[i].z, kp[i].w);
            *(uint2*)&sK[cur][(krow + i * 16) * 72 + kc4 * 4] = p;
        }
#pragma unroll
        for (int i = 0; i < 2; i++) {
            const int kb = (wave * 2 + i) * 8;
            uint4 p4;
            p4.x = pk_trunc(vp[i * 8 + 0], vp[i * 8 + 1]);
            p4.y = pk_trunc(vp[i * 8 + 2], vp[i * 8 + 3]);
            p4.z = pk_trunc(vp[i * 8 + 4], vp[i * 8 + 5]);
            p4.w = pk_trunc(vp[i * 8 + 6], vp[i * 8 + 7]);
            *(uint4*)&sVt[cur][lane * 72 + kb] = p4;
        }

        __syncthreads();

        unsigned long long mwN = 0;
        if (ki < 31) {
            const int kn = (ki + 1) * 64;
            mwN = Bt[(ki + 1) * 256];
#pragma unroll
            for (int i = 0; i < 4; i++)
                kp[i] = *(const float4*)(Kb + (size_t)(kn + krow + i * 16) * 64 + kc4 * 4);
#pragma unroll
            for (int i = 0; i < 2; i++) {
                const int kb = (wave * 2 + i) * 8;
#pragma unroll
                for (int j = 0; j < 8; j++)
                    vp[i * 8 + j] = Vb[(size_t)(kn + kb + j) * 64 + lane];
            }
        }

#pragma unroll
        for (int jk = 0; jk < 2; jk++) {
            bf16x8 aK[4];
#pragma unroll
            for (int dk = 0; dk < 4; dk++)
                aK[dk] = *(const bf16x8*)&sK[cur][(jk * 32 + l32) * 72 + dk * 16 + half * 8];
            bf16x8 bV[2][2];
#pragma unroll
            for (int p = 0; p < 2; p++)
#pragma unroll
                for (int db = 0; db < 2; db++)
                    bV[p][db] = *(const bf16x8*)&sVt[cur][(db * 32 + l32) * 72 + (jk * 2 + p) * 16 + half * 8];

            const unsigned b32 = (unsigned)(mw >> (jk * 32));
            const unsigned bsh = b32 >> (half * 4);

            f32x16 acc;
#pragma unroll
            for (int rg = 0; rg < 4; rg++) {
                const unsigned nib = bsh >> (rg * 8);
                acc[rg * 4 + 0] = (nib & 1u) ? NEGV : 0.f;
                acc[rg * 4 + 1] = (nib & 2u) ? NEGV : 0.f;
                acc[rg * 4 + 2] = (nib & 4u) ? NEGV : 0.f;
                acc[rg * 4 + 3] = (nib & 8u) ? NEGV : 0.f;
            }
#pragma unroll
            for (int dk = 0; dk < 4; dk++)
                acc = __builtin_amdgcn_mfma_f32_32x32x16_bf16(aK[dk], qF[dk], acc, 0, 0, 0);

#pragma unroll
            for (int p = 0; p < 2; p++) {
                const unsigned P0 = pk_trunc(acc[p * 8 + 0], acc[p * 8 + 1]);
                const unsigned P1 = pk_trunc(acc[p * 8 + 2], acc[p * 8 + 3]);
                const unsigned P2 = pk_trunc(acc[p * 8 + 4], acc[p * 8 + 5]);
                const unsigned P3 = pk_trunc(acc[p * 8 + 6], acc[p * 8 + 7]);
                auto r02 = __builtin_amdgcn_permlane32_swap(P0, P2, false, false);
                auto r13 = __builtin_amdgcn_permlane32_swap(P1, P3, false, false);
                union { bf16x8 v; unsigned u[4]; } aS;
                aS.u[0] = (unsigned)r02[0];
                aS.u[1] = (unsigned)r13[0];
                aS.u[2] = (unsigned)r02[1];
                aS.u[3] = (unsigned)r13[1];
#pragma unroll
                for (int db = 0; db < 2; db++)
                    Oacc[db] = __builtin_amdgcn_mfma_f32_32x32x16_bf16(aS.v, bV[p][db], Oacc[db], 0, 0, 0);
            }
        }

        mw = mwN;
    }

    float* Ob = Out + (size_t)bh * 2048 * 64;
#pragma unroll
    for (int r = 0; r < 16; r++) {
        const float v0 = Oacc[0][r], v1 = Oacc[1][r];
        float mx = fmaxf(v0, v1);
#pragma unroll
        for (int off = 1; off < 32; off <<= 1)
            mx = fmaxf(mx, __shfl_xor(mx, off, 64));
        float s = __expf(v0 - mx) + __expf(v1 - mx);
#pragma unroll
        for (int off = 1; off < 32; off <<= 1)
            s += __shfl_xor(s, off, 64);
        const float lse = mx + __logf(s);
        const int qrow = q0 + wave * 32 + (r & 3) + 8 * (r >> 2) + 4 * half;
        Ob[(size_t)qrow * 64 + l32]      = v0 - lse;
        Ob[(size_t)qrow * 64 + 32 + l32] = v1 - lse;
    }
}

extern "C" void kernel_launch(void* const* d_in, const int* in_sizes, int n_in,
                              void* d_out, int out_size, void* d_ws, size_t ws_size,
                              hipStream_t stream) {
    const float* Q = (const float*)d_in[0];
    const float* K = (const float*)d_in[1];
    const float* V = (const float*)d_in[2];
    const int*   M = (const int*)d_in[3];
    float* Out = (float*)d_out;
    unsigned long long* bitT = (unsigned long long*)d_ws;

    if (ws_size >= WS_NEED) {
        unsigned short* KV = (unsigned short*)((char*)d_ws + WS_KV_OFF);
        preconv<<<dim3(4096), dim3(256), 0, stream>>>(M, K, V, bitT, KV);
        attn_fast<<<dim3(1024), dim3(256), 0, stream>>>(Q, KV, bitT, Out);
    } else {
        mask_pack<<<dim3(2048), dim3(256), 0, stream>>>(M, bitT);
        attn_v10<<<dim3(1024), dim3(256), 0, stream>>>(Q, K, V, bitT, Out);
    }
}